// Round 1
// 197.589 us; speedup vs baseline: 1.0423x; 1.0423x over previous
//
#include <hip/hip_runtime.h>

// GradientInputLayer: B=64, C=2, L=64, N=16, BIN=360//16=22, EPS=1e-5
// x: (64, 2*64^3) f32 in {0,1}; out: (64,2,16,16) f32
//
// ws layout: [0, 262144)          uint8 bin table tab[i*4096 + j*64 + k]
//            [262144, 393216)     float g[128*256] accumulator (pair-major)
//            [393216, 1441792)    float mag[262144] = sqrt(i^2+j^2+k^2) LUT
//
// R3: no device fences / nt loads per-block. R4: wave-privatization neutral.
// R5: pipelining neutral. R6: scatter 38.8us even x-L3-hot (not BW-bound).
// R7: fewer flushes only -3us. R8 diagnostic: hot-pass compute = 19.4us,
//   VALUBusy 34%, bank-conflicts 0 => cost was the branchy flush construct.
// R9: branch-free RLE via unconditional LDS slot writes; no hot-loop atomics.
// R10 (this round): harness resets (512MiB ws poison fill @78us + x restore)
//   dominate dur_us and are untouchable; attack the ~45us kernel slice.
//   (1) mag LUT: hoist the 16 quarter-rate v_sqrt_f32 per thread out of the
//       scatter hot loop into bin_table (bitwise-identical values, L2-served
//       64B/thread reads). (2) byte-offset RLE addressing. (3) float4 norm.

#define BINS_PAD 80   // real bins are 0..68 (ax,az in 0..4); 69 = flush sentinel
#define SLOTS 10      // bins monotone along k: <=8 changes per 16-elem segment

__global__ __launch_bounds__(256)
void bin_table_kernel(unsigned char* __restrict__ tab,
                      float* __restrict__ g,
                      float* __restrict__ mag) {
    int v = blockIdx.x * 256 + threadIdx.x;          // 0..262143
    int i = v >> 12, j = (v >> 6) & 63, k = v & 63;
    double xc2 = (double)(j * j + k * k);            // x_comp^2
    double zc2 = (double)(i * i + j * j);            // z_comp^2
    double i2  = (double)(i * i);
    double k2  = (double)(k * k);
    const double T1 = 0.4040262258351568  * 0.4040262258351568;
    const double T2 = 0.9656887748070740  * 0.9656887748070740;
    const double T3 = 2.2460367739042161  * 2.2460367739042161;
    const double T4 = 28.636253282915602  * 28.636253282915602;
    // ax = floor(atan2(xc, i)*deg/22) == #{m : xc^2 > i^2 tan^2(22m)}; strict >
    // handles every atan2 edge case exactly (verified absmax 0.0).
    int ax = (xc2 > i2 * T1) + (xc2 > i2 * T2) + (xc2 > i2 * T3) + (xc2 > i2 * T4);
    int az = (k2 > zc2 * T1) + (k2 > zc2 * T2) + (k2 > zc2 * T3) + (k2 > zc2 * T4);
    tab[v] = (unsigned char)(ax * 16 + az);
    // mag LUT: EXACTLY the expression the scatter hot loop used to compute,
    // so values are bit-identical: sqrtf(fmaf(k, k, (float)(i*i+j*j))).
    float kf  = (float)k;
    float r2f = (float)(i * i + j * j);              // exact (< 2^24)
    mag[v] = sqrtf(fmaf(kf, kf, r2f));
    if (v < 32768) g[v] = 0.0f;                      // zero accumulator (ws is poisoned)
}

// Block = (pair p, i-slab), 256 threads. Thread owns j = tid>>2, k-segment
// (tid&3)*16..+15. Hot loop is 100% branch-free and atomic-free: per element,
// update (off, acc) with cndmask and UNCONDITIONALLY ds_write_b64
// (bin, acc) to slot[tid] + off. Since bin is monotone along k, each slot's
// final value is that run's complete sum. Phase 2 reduces slots -> hist via
// a few LDS-atomic rounds; one <=80-bin global-atomic flush per block.
__global__ __launch_bounds__(256)
void scatter_kernel(const float4* __restrict__ x4,
                    const uint4* __restrict__ tab4,
                    const float4* __restrict__ mag4,
                    float* __restrict__ g) {
    __shared__ unsigned long long slot[256][SLOTS];   // 20 KB
    __shared__ float hist[BINS_PAD];
    int tid = threadIdx.x;
    int p   = blockIdx.x >> 6;               // (b,c) pair 0..127
    int i   = blockIdx.x & 63;               // i-slab 0..63

    // init own slots to sentinel (bin=69, acc=+0.0f) — no sync needed before
    // phase 1 (each thread touches only its own slots)
    const unsigned long long SENT = ((unsigned long long)69u) << 32;
    #pragma unroll
    for (int s = 0; s < SLOTS; ++s) slot[tid][s] = SENT;
    if (tid < BINS_PAD) hist[tid] = 0.0f;

    // voxel float4 base for this thread: (j*64 + k0)/4 == 4*tid
    const float4* xs = x4 + (size_t)p * 65536 + (size_t)i * 1024 + 4 * (size_t)tid;
    const float4* ms = mag4 + (size_t)i * 1024 + 4 * (size_t)tid;   // L2-hot LUT
    uint4  tb  = tab4[i * 256 + tid];
    float4 xq0 = xs[0], xq1 = xs[1], xq2 = xs[2], xq3 = xs[3];
    float4 mq0 = ms[0], mq1 = ms[1], mq2 = ms[2], mq3 = ms[3];

    float4       xq[4] = {xq0, xq1, xq2, xq3};
    float4       mq[4] = {mq0, mq1, mq2, mq3};
    unsigned int uq[4] = {tb.x, tb.y, tb.z, tb.w};

    int          prev = -1;                  // != any bin => first write is slot 0
    unsigned int off  = (unsigned int)-8;    // first element bumps to 0
    float        acc  = 0.0f;
    char* myslot = (char*)slot[tid];

    #pragma unroll
    for (int q = 0; q < 4; ++q) {
        unsigned int u = uq[q];
        #pragma unroll
        for (int e = 0; e < 4; ++e) {
            float xe = (e == 0) ? xq[q].x : (e == 1) ? xq[q].y : (e == 2) ? xq[q].z : xq[q].w;
            float me = (e == 0) ? mq[q].x : (e == 1) ? mq[q].y : (e == 2) ? mq[q].z : mq[q].w;
            float val = xe * me;             // bitwise == old xe*sqrtf(fmaf(k,k,r2f))
            int   b   = (u >> (8 * e)) & 255;
            bool  ch  = (b != prev);
            off += ch ? 8u : 0u;
            acc  = ch ? val : (acc + val);
            prev = b;
            *(unsigned long long*)(myslot + off) =
                (((unsigned long long)(unsigned)b) << 32)
              | (unsigned long long)__float_as_uint(acc);
        }
    }
    __syncthreads();

    // phase 2: reduce this thread's slots into the block hist
    unsigned long long* mys = slot[tid];
    #pragma unroll
    for (int s = 0; s < SLOTS; ++s) {
        unsigned long long pk = mys[s];
        float av = __uint_as_float((unsigned int)pk);
        if (av != 0.0f) {
            unsigned int bb = (unsigned int)(pk >> 32);   // <= 69 < BINS_PAD
            atomicAdd(&hist[bb], av);
        }
    }
    __syncthreads();

    if (tid < BINS_PAD) {
        float hv = hist[tid];
        if (hv != 0.0f) atomicAdd(&g[p * 256 + tid], hv);
    }
}

// Single block: per-channel mean/var over (B, N, N) = 16384 values in double,
// then fused scale/shift write of all 32768 outputs. float4 path: 8 loads +
// 8 stores per thread instead of 32+32 (channel is constant within a float4:
// c = (float4_idx >> 6) & 1 since 256 floats = 64 float4 per (p,bin-row)).
__global__ __launch_bounds__(1024)
void norm_kernel(const float4* __restrict__ g4,
                 const float* __restrict__ gamma,
                 const float* __restrict__ beta,
                 float4* __restrict__ out4) {
    __shared__ double red[16][4];
    __shared__ float  coef[4];        // sc0, sc1, sh0, sh1
    int t = threadIdx.x;
    float4 vals[8];
    double s0 = 0.0, s1 = 0.0, q0 = 0.0, q1 = 0.0;
    #pragma unroll
    for (int n = 0; n < 8; ++n) {
        int idx = t + n * 1024;                       // float4 index 0..8191
        float4 v = g4[idx];
        vals[n] = v;
        double a = (double)v.x + (double)v.y + (double)v.z + (double)v.w;
        double b = (double)v.x * (double)v.x + (double)v.y * (double)v.y
                 + (double)v.z * (double)v.z + (double)v.w * (double)v.w;
        if ((idx >> 6) & 1) { s1 += a; q1 += b; }
        else                { s0 += a; q0 += b; }
    }
    #pragma unroll
    for (int offm = 32; offm > 0; offm >>= 1) {
        s0 += __shfl_down(s0, offm);
        s1 += __shfl_down(s1, offm);
        q0 += __shfl_down(q0, offm);
        q1 += __shfl_down(q1, offm);
    }
    int wave = t >> 6;
    if ((t & 63) == 0) {
        red[wave][0] = s0; red[wave][1] = s1; red[wave][2] = q0; red[wave][3] = q1;
    }
    __syncthreads();
    if (t == 0) {
        double S0 = 0, S1 = 0, Q0 = 0, Q1 = 0;
        for (int wv = 0; wv < 16; ++wv) {
            S0 += red[wv][0]; S1 += red[wv][1]; Q0 += red[wv][2]; Q1 += red[wv][3];
        }
        const double inv_n = 1.0 / 16384.0;
        double m0 = S0 * inv_n, m1 = S1 * inv_n;
        double v0 = Q0 * inv_n - m0 * m0;
        double v1 = Q1 * inv_n - m1 * m1;
        double r0 = 1.0 / sqrt(v0 + 1e-5);
        double r1 = 1.0 / sqrt(v1 + 1e-5);
        float g0 = gamma[0], g1 = gamma[1], b0 = beta[0], b1 = beta[1];
        coef[0] = (float)r0 * g0;
        coef[1] = (float)r1 * g1;
        coef[2] = b0 - (float)(m0 * r0) * g0;
        coef[3] = b1 - (float)(m1 * r1) * g1;
    }
    __syncthreads();
    float sc0 = coef[0], sc1 = coef[1], sh0 = coef[2], sh1 = coef[3];
    #pragma unroll
    for (int n = 0; n < 8; ++n) {
        int idx = t + n * 1024;
        int c = (idx >> 6) & 1;
        float sc = c ? sc1 : sc0;
        float sh = c ? sh1 : sh0;
        float4 v = vals[n];
        float4 o;
        o.x = v.x * sc + sh; o.y = v.y * sc + sh;
        o.z = v.z * sc + sh; o.w = v.w * sc + sh;
        out4[idx] = o;
    }
}

extern "C" void kernel_launch(void* const* d_in, const int* in_sizes, int n_in,
                              void* d_out, int out_size, void* d_ws, size_t ws_size,
                              hipStream_t stream) {
    const float* x     = (const float*)d_in[0];
    const float* gamma = (const float*)d_in[1];
    const float* beta  = (const float*)d_in[2];
    float* out = (float*)d_out;

    unsigned char* tab = (unsigned char*)d_ws;
    float*         g   = (float*)((char*)d_ws + 262144);
    float*         mag = (float*)((char*)d_ws + 393216);

    bin_table_kernel<<<1024, 256, 0, stream>>>(tab, g, mag);
    scatter_kernel<<<8192, 256, 0, stream>>>((const float4*)x, (const uint4*)tab,
                                             (const float4*)mag, g);
    norm_kernel<<<1, 1024, 0, stream>>>((const float4*)g, gamma, beta, (float4*)out);
}